// Round 1
// baseline (3762.111 us; speedup 1.0000x reference)
//
#include <hip/hip_runtime.h>
#include <hip/hip_fp16.h>

typedef unsigned int u32;
typedef unsigned short u16;
typedef _Float16 half2v __attribute__((ext_vector_type(2)));

#define N_UNITS 512
#define N_ORDER 256
#define N_T     1024
#define N_B     64
#define KWG     4
#define PKT_STRIDE 288   // dwords per (parity,b,q) packet: 128 m + 128 h + 6 u + pad

__device__ inline float dot2f(u32 a, u32 b, float acc) {
    return __builtin_amdgcn_fdot2(__builtin_bit_cast(half2v, a),
                                  __builtin_bit_cast(half2v, b), acc, false);
}
__device__ inline u16 f2h_bits(float v) {
    _Float16 f = (_Float16)v;
    return __builtin_bit_cast(u16, f);
}
__device__ inline float hbits2f(u32 dw) {
    u16 s = (u16)(dw & 0xFFFFu);
    _Float16 f = __builtin_bit_cast(_Float16, s);
    return (float)f;
}
__device__ inline u32 pack_h2(float a, float b) {
    return (u32)f2h_bits(a) | ((u32)f2h_bits(b) << 16);
}
__device__ inline u32 aload(const u32* p) {
    return __hip_atomic_load(p, __ATOMIC_RELAXED, __HIP_MEMORY_SCOPE_AGENT);
}
__device__ inline void astore(u32* p, u32 v) {
    __hip_atomic_store(p, v, __ATOMIC_RELAXED, __HIP_MEMORY_SCOPE_AGENT);
}

// hk2[kk][c] = half2(hk[2kk][c], hk[2kk+1][c]),  kk<256, c<512
__global__ __launch_bounds__(256)
void prep_hk(const float* __restrict__ hk, u32* __restrict__ hk2) {
    int tid = blockIdx.x * 256 + threadIdx.x;   // 131072 total
    int kk = tid >> 9, c = tid & 511;
    hk2[tid] = pack_h2(hk[(2 * kk) * 512 + c], hk[(2 * kk + 1) * 512 + c]);
}

// AMK = mk + AT@mk  (fp16, j-pair packed);  BMK = BT@mk (fp32)
__global__ __launch_bounds__(512)
void prep_amk(const float* __restrict__ mk, const float* __restrict__ at,
              const float* __restrict__ bt,
              u32* __restrict__ amk2, float* __restrict__ bmk) {
    int bj = blockIdx.x, c = threadIdx.x;
    if (bj < 128) {
        int j0 = 2 * bj, j1 = j0 + 1;
        float a0 = mk[j0 * 512 + c];
        float a1 = mk[j1 * 512 + c];
        #pragma unroll 8
        for (int k = 0; k < 256; ++k) {
            float w = mk[k * 512 + c];
            a0 = fmaf(at[j0 * 256 + k], w, a0);
            a1 = fmaf(at[j1 * 256 + k], w, a1);
        }
        amk2[bj * 512 + c] = pack_h2(a0, a1);
    } else {
        float s = 0.f;
        #pragma unroll 8
        for (int k = 0; k < 256; ++k) s = fmaf(bt[k], mk[k * 512 + c], s);
        bmk[c] = s;
    }
}

// K=4 WGs per batch; grid=256 (1 WG/CU). g: b=g&63, q=g>>6 (same XCD mod-8).
// WG q owns h cols [128q,128q+128), m cols [64q,64q+64).
// Self-validating packets (epoch in each dword's high16), 2-parity reuse.
// This revision: vectorized LDS (b128 broadcasts), 4-acc dot chains, parallel
// h/m finalize waves, early own-slice compute during the peer-spin window,
// 8-dword poll chunks, no tid0 funnel.
__global__ __launch_bounds__(512, 2)
void lmu_main(const float* __restrict__ x, const float* __restrict__ ie,
              const float* __restrict__ he, const float* __restrict__ me,
              const float* __restrict__ ik, const float* __restrict__ bt,
              const float* __restrict__ at,
              const u32* __restrict__ hk2, const u32* __restrict__ amk2,
              const float* __restrict__ bmk,
              u32* __restrict__ pkt, float* __restrict__ out) {
    __shared__ float xs[N_T];
    __shared__ float he_sl[128], ik_sl[128], bmk_sl[128];
    __shared__ float me_sl[64], bt_sl[64];
    __shared__ __align__(16) u16 h_h16[N_UNITS];     // full h, fp16
    __shared__ __align__(16) u16 m_hi16[N_ORDER], m_lo16[N_ORDER];
    __shared__ __align__(16) float mf[N_ORDER];      // full m, fp32(-ish)
    __shared__ __align__(16) float zbuf[512], ampart[512];
    __shared__ float upart[4];                       // peer u partials
    __shared__ float upw_s[3];                       // own u partials (2 h-waves + m-wave)

    const int tid  = threadIdx.x;
    const int g    = blockIdx.x;
    const int b    = g & 63;
    const int q    = g >> 6;
    const int kg   = tid >> 7;        // 0..3 (hk/AMK k-group)
    const int cl   = tid & 127;       // col within own h slice
    const int kg8  = tid >> 6;        // 0..7 (AT k-group)
    const int lane = tid & 63;
    const bool is_early = (kg == q);  // this thread's k-rows = own slice

    // poll-role precompute: 99 poll threads live in the kg==(q+1)&3 block
    // (never overlaps the early-compute block). 3 peers x 33 chunks.
    const int P0 = 128 * ((q + 1) & 3);
    const int tp = tid - P0;
    const bool is_poll = (tp >= 0 && tp < 99);
    int ch = 0, q2 = 0;
    if (is_poll) {
        int pi = tp / 33;             // 0..2 peer index
        ch = tp - 33 * pi;            // 0..32 chunk
        q2 = pi + (pi >= q ? 1 : 0);
    }

    // ---- preload LDS ----
    for (int i = tid; i < N_T; i += 512) xs[i] = x[b * N_T + i];
    if (tid < 128) {
        he_sl[tid]  = he[128 * q + tid];
        ik_sl[tid]  = ik[128 * q + tid];
        bmk_sl[tid] = bmk[128 * q + tid];
    }
    if (tid < 64) { me_sl[tid] = me[64 * q + tid]; bt_sl[tid] = bt[64 * q + tid]; }
    h_h16[tid] = 0;
    if (tid < 256) { m_hi16[tid] = 0; m_lo16[tid] = 0; mf[tid] = 0.f; }
    if (tid < 4) upart[tid] = 0.f;
    if (tid < 3) upw_s[tid] = 0.f;
    const float ie0 = ie[0];

    // ---- weights into registers (once) ----
    u32 hk_w[64];
    #pragma unroll
    for (int i = 0; i < 64; ++i)
        hk_w[i] = hk2[(size_t)(64 * kg + i) * 512 + 128 * q + cl];
    u32 amk_w[32];
    #pragma unroll
    for (int i = 0; i < 32; ++i)
        amk_w[i] = amk2[(size_t)(32 * kg + i) * 512 + 128 * q + cl];
    float at_w[32];
    #pragma unroll
    for (int i = 0; i < 32; ++i)
        at_w[i] = at[(size_t)(32 * kg8 + i) * 256 + 64 * q + lane];

    __syncthreads();

    const uint4*  h4  = reinterpret_cast<const uint4*>(h_h16)  + 16 * kg;
    const uint4*  mh4 = reinterpret_cast<const uint4*>(m_hi16) + 8 * kg;
    const uint4*  ml4 = reinterpret_cast<const uint4*>(m_lo16) + 8 * kg;
    const float4* mf4 = reinterpret_cast<const float4*>(mf)    + 8 * kg8;
    float* outb = out + (size_t)b * N_T * N_UNITS;

    // z + AT partials for this thread's (kg, cl): b128 uniform broadcasts,
    // 4 independent accumulator chains.
    auto compute_partials = [&]() {
        float z0 = 0.f, z1 = 0.f, z2 = 0.f, z3 = 0.f;
        #pragma unroll
        for (int j = 0; j < 16; ++j) {
            uint4 h = h4[j];
            z0 = dot2f(h.x, hk_w[4 * j + 0], z0);
            z1 = dot2f(h.y, hk_w[4 * j + 1], z1);
            z2 = dot2f(h.z, hk_w[4 * j + 2], z2);
            z3 = dot2f(h.w, hk_w[4 * j + 3], z3);
        }
        #pragma unroll
        for (int j = 0; j < 8; ++j) {
            uint4 mh = mh4[j];
            uint4 ml = ml4[j];
            z0 = dot2f(mh.x, amk_w[4 * j + 0], z0); z0 = dot2f(ml.x, amk_w[4 * j + 0], z0);
            z1 = dot2f(mh.y, amk_w[4 * j + 1], z1); z1 = dot2f(ml.y, amk_w[4 * j + 1], z1);
            z2 = dot2f(mh.z, amk_w[4 * j + 2], z2); z2 = dot2f(ml.z, amk_w[4 * j + 2], z2);
            z3 = dot2f(mh.w, amk_w[4 * j + 3], z3); z3 = dot2f(ml.w, amk_w[4 * j + 3], z3);
        }
        zbuf[tid] = (z0 + z1) + (z2 + z3);
        float a0 = 0.f, a1 = 0.f, a2 = 0.f, a3 = 0.f;
        #pragma unroll
        for (int j = 0; j < 8; ++j) {
            float4 m4 = mf4[j];
            a0 = fmaf(m4.x, at_w[4 * j + 0], a0);
            a1 = fmaf(m4.y, at_w[4 * j + 1], a1);
            a2 = fmaf(m4.z, at_w[4 * j + 2], a2);
            a3 = fmaf(m4.w, at_w[4 * j + 3], a3);
        }
        ampart[tid] = (a0 + a1) + (a2 + a3);
    };

    for (int t = 0; t < N_T; ++t) {
        if (t > 0) {
            // ---- A: early own-slice partials (inputs written by own WG last step)
            if (is_early) compute_partials();
            // ---- B: consume peers' packets (overlaps with A)
            if (is_poll) {
                const u32 ep = (u32)t;
                const u32* base = pkt + (size_t)(((t - 1) & 1) * 256 + b * 4 + q2) * PKT_STRIDE;
                if (ch < 32) {
                    const u32* p8 = base + 8 * ch;
                    u32 d0, d1, d2, d3, d4, d5, d6, d7;
                    for (;;) {
                        d0 = aload(p8 + 0); d1 = aload(p8 + 1);
                        d2 = aload(p8 + 2); d3 = aload(p8 + 3);
                        d4 = aload(p8 + 4); d5 = aload(p8 + 5);
                        d6 = aload(p8 + 6); d7 = aload(p8 + 7);
                        u32 bad = ((((d0 >> 16) ^ ep) | ((d1 >> 16) ^ ep)) |
                                   (((d2 >> 16) ^ ep) | ((d3 >> 16) ^ ep))) |
                                  ((((d4 >> 16) ^ ep) | ((d5 >> 16) ^ ep)) |
                                   (((d6 >> 16) ^ ep) | ((d7 >> 16) ^ ep)));
                        if (bad == 0) break;
                    }
                    if (ch < 16) {       // m: j-locals 4ch..4ch+3 (hi,lo dword pairs)
                        int idx = 64 * q2 + 4 * ch;
                        float4 v;
                        v.x = hbits2f(d0) + hbits2f(d1);
                        v.y = hbits2f(d2) + hbits2f(d3);
                        v.z = hbits2f(d4) + hbits2f(d5);
                        v.w = hbits2f(d6) + hbits2f(d7);
                        *reinterpret_cast<float4*>(mf + idx) = v;
                        u32* mhp = reinterpret_cast<u32*>(m_hi16);
                        u32* mlp = reinterpret_cast<u32*>(m_lo16);
                        mhp[(idx >> 1) + 0] = (d0 & 0xFFFFu) | (d2 << 16);
                        mhp[(idx >> 1) + 1] = (d4 & 0xFFFFu) | (d6 << 16);
                        mlp[(idx >> 1) + 0] = (d1 & 0xFFFFu) | (d3 << 16);
                        mlp[(idx >> 1) + 1] = (d5 & 0xFFFFu) | (d7 << 16);
                    } else {             // h: cols 8(ch-16)..+7 of slice q2
                        int i0 = (128 * q2 + 8 * ch - 128) >> 1;
                        u32* hhp = reinterpret_cast<u32*>(h_h16);
                        hhp[i0 + 0] = (d0 & 0xFFFFu) | (d1 << 16);
                        hhp[i0 + 1] = (d2 & 0xFFFFu) | (d3 << 16);
                        hhp[i0 + 2] = (d4 & 0xFFFFu) | (d5 << 16);
                        hhp[i0 + 3] = (d6 & 0xFFFFu) | (d7 << 16);
                    }
                } else {                 // u partials: 3 hi/lo pairs
                    const u32* p6 = base + 256;
                    u32 d0, d1, d2, d3, d4, d5;
                    for (;;) {
                        d0 = aload(p6 + 0); d1 = aload(p6 + 1); d2 = aload(p6 + 2);
                        d3 = aload(p6 + 3); d4 = aload(p6 + 4); d5 = aload(p6 + 5);
                        u32 bad = ((((d0 >> 16) ^ ep) | ((d1 >> 16) ^ ep)) |
                                   (((d2 >> 16) ^ ep) | ((d3 >> 16) ^ ep))) |
                                  (((d4 >> 16) ^ ep) | ((d5 >> 16) ^ ep));
                        if (bad == 0) break;
                    }
                    upart[q2] = (hbits2f(d0) + hbits2f(d1)) + (hbits2f(d2) + hbits2f(d3))
                              + (hbits2f(d4) + hbits2f(d5));
                }
            }
        }
        __syncthreads();                                   // B1

        // ---- C: remaining partials (peer-slice k-rows) ----
        if (!is_early || t == 0) compute_partials();
        __syncthreads();                                   // B2

        // ---- D: finalize. waves 0-1: h; wave 2: m (parallel). ----
        float u = 0.f, hnew = 0.f, mnew = 0.f;
        u16 mhi_b = 0, mlo_b = 0;
        if (tid < 192) {
            u = ((upart[0] + upart[1]) + (upart[2] + upart[3]))
              + ((upw_s[0] + upw_s[1]) + upw_s[2]) + xs[t] * ie0;
        }
        if (tid < 128) {
            float zf = (zbuf[tid] + zbuf[tid + 128]) + (zbuf[tid + 256] + zbuf[tid + 384])
                     + xs[t] * ik_sl[tid] + u * bmk_sl[tid];
            hnew = tanhf(zf);
            outb[(size_t)t * N_UNITS + 128 * q + tid] = hnew;   // issue early; drains at B3
            h_h16[128 * q + tid] = f2h_bits(hnew);
        } else if (tid < 192) {
            const int jl = tid - 128;
            const int J  = 64 * q + jl;
            mnew = mf[J] + u * bt_sl[jl];
            #pragma unroll
            for (int gi = 0; gi < 8; ++gi) mnew += ampart[jl + 64 * gi];
            _Float16 hi = (_Float16)mnew;
            float lo = mnew - (float)hi;
            mhi_b = __builtin_bit_cast(u16, hi);
            mlo_b = f2h_bits(lo);
            mf[J] = mnew;                // own slice stays exact fp32
            m_hi16[J] = mhi_b;
            m_lo16[J] = mlo_b;
        }

        float up_red = 0.f;
        if (t < N_T - 1) {
            // ---- publish own slices ----
            const u32 eph = (u32)(t + 1) << 16;
            u32* myb = pkt + (size_t)((t & 1) * 256 + b * 4 + q) * PKT_STRIDE;
            if (tid < 128) {
                astore(myb + 128 + tid, (u32)f2h_bits(hnew) | eph);
            } else if (tid < 192) {
                const int jl = tid - 128;
                astore(myb + 2 * jl,     (u32)mhi_b | eph);
                astore(myb + 2 * jl + 1, (u32)mlo_b | eph);
            }
            // ---- u-partials for step t+1: 3 waves reduce in parallel ----
            float up = 0.f;
            if (tid < 128)      up = hnew * he_sl[tid];
            else if (tid < 192) up = mnew * me_sl[tid - 128];
            #pragma unroll
            for (int off = 32; off > 0; off >>= 1) up += __shfl_down(up, off);
            if (lane == 0 && tid < 192) {
                const int w = tid >> 6;
                _Float16 hi = (_Float16)up;
                float lo = up - (float)hi;
                astore(myb + 256 + 2 * w,     (u32)__builtin_bit_cast(u16, hi) | eph);
                astore(myb + 256 + 2 * w + 1, (u32)f2h_bits(lo) | eph);
                up_red = up;
            }
        }
        __syncthreads();                                   // B3 (zbuf/state WAR fence)
        if (lane == 0 && tid < 192) upw_s[tid >> 6] = up_red;  // self u-partials, read next D
    }
}

extern "C" void kernel_launch(void* const* d_in, const int* in_sizes, int n_in,
                              void* d_out, int out_size, void* d_ws, size_t ws_size,
                              hipStream_t stream) {
    const float* x  = (const float*)d_in[0];
    const float* ie = (const float*)d_in[1];
    const float* he = (const float*)d_in[2];
    const float* me = (const float*)d_in[3];
    const float* ik = (const float*)d_in[4];
    const float* hk = (const float*)d_in[5];
    const float* mk = (const float*)d_in[6];
    const float* at = (const float*)d_in[7];
    const float* bt = (const float*)d_in[8];

    u32*   hk2  = (u32*)d_ws;                   // 131072 u32 = 512 KB
    u32*   amk2 = hk2 + 256 * 512;              //  65536 u32 = 256 KB
    float* bmk  = (float*)(amk2 + 128 * 512);   //    512 f32 =   2 KB
    u32*   pkt  = (u32*)(bmk + 512);            // 2*64*4*288 u32 = 576 KB

    prep_hk<<<512, 256, 0, stream>>>(hk, hk2);
    prep_amk<<<129, 512, 0, stream>>>(mk, at, bt, amk2, bmk);
    lmu_main<<<N_B * KWG, 512, 0, stream>>>(x, ie, he, me, ik, bt, at,
                                            hk2, amk2, bmk, pkt, (float*)d_out);
}

// Round 2
// 3211.225 us; speedup vs baseline: 1.1716x; 1.1716x over previous
//
#include <hip/hip_runtime.h>
#include <hip/hip_fp16.h>

typedef unsigned int u32;
typedef unsigned short u16;
typedef _Float16 half2v __attribute__((ext_vector_type(2)));

#define N_UNITS 512
#define N_ORDER 256
#define N_T     1024
#define N_B     64
#define KWG     4
#define PKT_STRIDE 288   // dwords per (parity,b,q) packet: 128 m + 128 h + 6 u + pad

__device__ inline float dot2f(u32 a, u32 b, float acc) {
    return __builtin_amdgcn_fdot2(__builtin_bit_cast(half2v, a),
                                  __builtin_bit_cast(half2v, b), acc, false);
}
__device__ inline u16 f2h_bits(float v) {
    _Float16 f = (_Float16)v;
    return __builtin_bit_cast(u16, f);
}
__device__ inline float hbits2f(u32 dw) {
    u16 s = (u16)(dw & 0xFFFFu);
    _Float16 f = __builtin_bit_cast(_Float16, s);
    return (float)f;
}
__device__ inline u32 pack_h2(float a, float b) {
    return (u32)f2h_bits(a) | ((u32)f2h_bits(b) << 16);
}
__device__ inline u32 aload(const u32* p) {
    return __hip_atomic_load(p, __ATOMIC_RELAXED, __HIP_MEMORY_SCOPE_AGENT);
}
__device__ inline void astore(u32* p, u32 v) {
    __hip_atomic_store(p, v, __ATOMIC_RELAXED, __HIP_MEMORY_SCOPE_AGENT);
}

// hk2[kk][c] = half2(hk[2kk][c], hk[2kk+1][c]),  kk<256, c<512
__global__ __launch_bounds__(256)
void prep_hk(const float* __restrict__ hk, u32* __restrict__ hk2) {
    int tid = blockIdx.x * 256 + threadIdx.x;   // 131072 total
    int kk = tid >> 9, c = tid & 511;
    hk2[tid] = pack_h2(hk[(2 * kk) * 512 + c], hk[(2 * kk + 1) * 512 + c]);
}

// AMK = mk + AT@mk  (fp16, j-pair packed);  BMK = BT@mk (fp32)
__global__ __launch_bounds__(512)
void prep_amk(const float* __restrict__ mk, const float* __restrict__ at,
              const float* __restrict__ bt,
              u32* __restrict__ amk2, float* __restrict__ bmk) {
    int bj = blockIdx.x, c = threadIdx.x;
    if (bj < 128) {
        int j0 = 2 * bj, j1 = j0 + 1;
        float a0 = mk[j0 * 512 + c];
        float a1 = mk[j1 * 512 + c];
        #pragma unroll 8
        for (int k = 0; k < 256; ++k) {
            float w = mk[k * 512 + c];
            a0 = fmaf(at[j0 * 256 + k], w, a0);
            a1 = fmaf(at[j1 * 256 + k], w, a1);
        }
        amk2[bj * 512 + c] = pack_h2(a0, a1);
    } else {
        float s = 0.f;
        #pragma unroll 8
        for (int k = 0; k < 256; ++k) s = fmaf(bt[k], mk[k * 512 + c], s);
        bmk[c] = s;
    }
}

// K=4 WGs per batch; grid=256 (1 WG/CU). g: b=g&63, q=g>>6 (same XCD mod-8).
// WG q owns h cols [128q,128q+128), m cols [64q,64q+64).
// Self-validating packets (epoch in each dword's high16), 2-parity reuse.
// Round-2: baseline phase structure (all waves compute after B1, 195-thread
// 4-dword poll) + b128 broadcast LDS reads, 4-acc dot chains, parallel h/m
// finalize waves, publish-before-out ordering, per-wave u publish (no funnel).
__global__ __launch_bounds__(512, 2)
void lmu_main(const float* __restrict__ x, const float* __restrict__ ie,
              const float* __restrict__ he, const float* __restrict__ me,
              const float* __restrict__ ik, const float* __restrict__ bt,
              const float* __restrict__ at,
              const u32* __restrict__ hk2, const u32* __restrict__ amk2,
              const float* __restrict__ bmk,
              u32* __restrict__ pkt, float* __restrict__ out) {
    __shared__ float xs[N_T];
    __shared__ float he_sl[128], ik_sl[128], bmk_sl[128];
    __shared__ float me_sl[64], bt_sl[64];
    __shared__ __align__(16) u16 h_h16[N_UNITS];     // full h, fp16
    __shared__ __align__(16) u16 m_hi16[N_ORDER], m_lo16[N_ORDER];
    __shared__ __align__(16) float mf[N_ORDER];      // full m, fp32(-ish)
    __shared__ __align__(16) float zbuf[512], ampart[512];
    __shared__ float upart[4];                       // peer u partials
    __shared__ float upw_s[3];                       // own u partials (2 h-waves + m-wave)

    const int tid  = threadIdx.x;
    const int g    = blockIdx.x;
    const int b    = g & 63;
    const int q    = g >> 6;
    const int kg   = tid >> 7;        // 0..3 (hk/AMK k-group)
    const int cl   = tid & 127;       // col within own h slice
    const int kg8  = tid >> 6;        // 0..7 (AT k-group)
    const int jl   = tid & 63;
    const int J    = 64 * q + jl;
    const int lane = tid & 63;

    // ---- preload LDS ----
    for (int i = tid; i < N_T; i += 512) xs[i] = x[b * N_T + i];
    if (tid < 128) {
        he_sl[tid]  = he[128 * q + tid];
        ik_sl[tid]  = ik[128 * q + tid];
        bmk_sl[tid] = bmk[128 * q + tid];
    }
    if (tid < 64) { me_sl[tid] = me[J]; bt_sl[tid] = bt[J]; }
    h_h16[tid] = 0;
    if (tid < 256) { m_hi16[tid] = 0; m_lo16[tid] = 0; mf[tid] = 0.f; }
    if (tid < 4) upart[tid] = 0.f;
    if (tid < 3) upw_s[tid] = 0.f;
    const float ie0 = ie[0];

    // ---- weights into registers (once) ----
    u32 hk_w[64];
    #pragma unroll
    for (int i = 0; i < 64; ++i)
        hk_w[i] = hk2[(size_t)(64 * kg + i) * 512 + 128 * q + cl];
    u32 amk_w[32];
    #pragma unroll
    for (int i = 0; i < 32; ++i)
        amk_w[i] = amk2[(size_t)(32 * kg + i) * 512 + 128 * q + cl];
    float at_w[32];
    #pragma unroll
    for (int i = 0; i < 32; ++i)
        at_w[i] = at[(size_t)(32 * kg8 + i) * 256 + J];

    __syncthreads();

    const uint4*  h4  = reinterpret_cast<const uint4*>(h_h16)  + 16 * kg;
    const uint4*  mh4 = reinterpret_cast<const uint4*>(m_hi16) + 8 * kg;
    const uint4*  ml4 = reinterpret_cast<const uint4*>(m_lo16) + 8 * kg;
    const float4* mf4 = reinterpret_cast<const float4*>(mf)    + 8 * kg8;
    float* outb = out + (size_t)b * N_T * N_UNITS;

    for (int t = 0; t < N_T; ++t) {
        // ---- consume peers' packets (h_{t-1}, m_{t-1}, u-partials) ----
        if (t > 0) {
            const u32 ep  = (u32)t;
            const int par = (t - 1) & 1;
            if (tid < 195) {
                int pi = (tid < 192) ? (tid >> 6) : (tid - 192);
                int q2 = pi + (pi >= q ? 1 : 0);
                const u32* base = pkt + (size_t)(par * 256 + b * 4 + q2) * PKT_STRIDE;
                if (tid < 192) {
                    int i = tid & 63;
                    u32 d0, d1, d2, d3;
                    for (;;) {
                        d0 = aload(base + 4 * i + 0);
                        d1 = aload(base + 4 * i + 1);
                        d2 = aload(base + 4 * i + 2);
                        d3 = aload(base + 4 * i + 3);
                        if (((((d0 >> 16) ^ ep) | ((d1 >> 16) ^ ep)) |
                             (((d2 >> 16) ^ ep) | ((d3 >> 16) ^ ep))) == 0) break;
                    }
                    if (i < 32) {          // m: j = 2i, 2i+1 (hi,lo dword pairs)
                        int idx = 64 * q2 + 2 * i;       // even
                        float2 v;
                        v.x = hbits2f(d0) + hbits2f(d1);
                        v.y = hbits2f(d2) + hbits2f(d3);
                        *reinterpret_cast<float2*>(mf + idx) = v;
                        reinterpret_cast<u32*>(m_hi16)[idx >> 1] = (d0 & 0xFFFFu) | (d2 << 16);
                        reinterpret_cast<u32*>(m_lo16)[idx >> 1] = (d1 & 0xFFFFu) | (d3 << 16);
                    } else {               // h: c = 4i-128 .. +3
                        int i0 = (128 * q2 + 4 * i - 128) >> 1;
                        u32* hhp = reinterpret_cast<u32*>(h_h16);
                        hhp[i0 + 0] = (d0 & 0xFFFFu) | (d1 << 16);
                        hhp[i0 + 1] = (d2 & 0xFFFFu) | (d3 << 16);
                    }
                } else {                   // u partials: 3 hi/lo pairs
                    const u32* p6 = base + 256;
                    u32 d0, d1, d2, d3, d4, d5;
                    for (;;) {
                        d0 = aload(p6 + 0); d1 = aload(p6 + 1); d2 = aload(p6 + 2);
                        d3 = aload(p6 + 3); d4 = aload(p6 + 4); d5 = aload(p6 + 5);
                        u32 bad = ((((d0 >> 16) ^ ep) | ((d1 >> 16) ^ ep)) |
                                   (((d2 >> 16) ^ ep) | ((d3 >> 16) ^ ep))) |
                                  (((d4 >> 16) ^ ep) | ((d5 >> 16) ^ ep));
                        if (bad == 0) break;
                    }
                    upart[q2] = (hbits2f(d0) + hbits2f(d1)) + (hbits2f(d2) + hbits2f(d3))
                              + (hbits2f(d4) + hbits2f(d5));
                }
            }
        }
        __syncthreads();                                   // B1

        // ---- z + AT partials (all threads): b128 broadcasts, 4 acc chains ----
        {
            float z0 = 0.f, z1 = 0.f, z2 = 0.f, z3 = 0.f;
            #pragma unroll
            for (int j = 0; j < 16; ++j) {
                uint4 h = h4[j];
                z0 = dot2f(h.x, hk_w[4 * j + 0], z0);
                z1 = dot2f(h.y, hk_w[4 * j + 1], z1);
                z2 = dot2f(h.z, hk_w[4 * j + 2], z2);
                z3 = dot2f(h.w, hk_w[4 * j + 3], z3);
            }
            #pragma unroll
            for (int j = 0; j < 8; ++j) {
                uint4 mh = mh4[j];
                uint4 ml = ml4[j];
                z0 = dot2f(mh.x, amk_w[4 * j + 0], z0); z0 = dot2f(ml.x, amk_w[4 * j + 0], z0);
                z1 = dot2f(mh.y, amk_w[4 * j + 1], z1); z1 = dot2f(ml.y, amk_w[4 * j + 1], z1);
                z2 = dot2f(mh.z, amk_w[4 * j + 2], z2); z2 = dot2f(ml.z, amk_w[4 * j + 2], z2);
                z3 = dot2f(mh.w, amk_w[4 * j + 3], z3); z3 = dot2f(ml.w, amk_w[4 * j + 3], z3);
            }
            zbuf[tid] = (z0 + z1) + (z2 + z3);
            float a0 = 0.f, a1 = 0.f, a2 = 0.f, a3 = 0.f;
            #pragma unroll
            for (int j = 0; j < 8; ++j) {
                float4 m4 = mf4[j];
                a0 = fmaf(m4.x, at_w[4 * j + 0], a0);
                a1 = fmaf(m4.y, at_w[4 * j + 1], a1);
                a2 = fmaf(m4.z, at_w[4 * j + 2], a2);
                a3 = fmaf(m4.w, at_w[4 * j + 3], a3);
            }
            ampart[tid] = (a0 + a1) + (a2 + a3);
        }
        __syncthreads();                                   // B2

        // ---- finalize: waves 0-1: h (publish first); wave 2: m (parallel) ----
        const bool pub = (t < N_T - 1);
        const u32 eph  = (u32)(t + 1) << 16;
        u32* myb = pkt + (size_t)((t & 1) * 256 + b * 4 + q) * PKT_STRIDE;
        float u = 0.f, hnew = 0.f, mnew = 0.f;
        if (tid < 192) {
            u = ((upart[0] + upart[1]) + (upart[2] + upart[3]))
              + ((upw_s[0] + upw_s[1]) + upw_s[2]) + xs[t] * ie0;
        }
        if (tid < 128) {
            float zf = (zbuf[tid] + zbuf[tid + 128]) + (zbuf[tid + 256] + zbuf[tid + 384])
                     + xs[t] * ik_sl[tid] + u * bmk_sl[tid];
            hnew = tanhf(zf);
            u16 hb = f2h_bits(hnew);
            if (pub) astore(myb + 128 + tid, (u32)hb | eph);   // publish ASAP
            outb[(size_t)t * N_UNITS + 128 * q + tid] = hnew;
            h_h16[128 * q + tid] = hb;
        } else if (tid < 192) {
            mnew = mf[J] + u * bt_sl[jl];
            #pragma unroll
            for (int gi = 0; gi < 8; ++gi) mnew += ampart[jl + 64 * gi];
            _Float16 hi = (_Float16)mnew;
            float lo = mnew - (float)hi;
            u16 mhi_b = __builtin_bit_cast(u16, hi);
            u16 mlo_b = f2h_bits(lo);
            if (pub) {                                          // publish ASAP
                astore(myb + 2 * jl,     (u32)mhi_b | eph);
                astore(myb + 2 * jl + 1, (u32)mlo_b | eph);
            }
            mf[J] = mnew;                // own slice stays exact fp32
            m_hi16[J] = mhi_b;
            m_lo16[J] = mlo_b;
        }

        // ---- own u-partials for step t+1: 3 waves reduce + publish in parallel ----
        float up_red = 0.f;
        if (pub && tid < 192) {
            float up = (tid < 128) ? hnew * he_sl[tid] : mnew * me_sl[tid - 128];
            #pragma unroll
            for (int off = 32; off > 0; off >>= 1) up += __shfl_down(up, off);
            if (lane == 0) {
                const int w = tid >> 6;
                _Float16 hi = (_Float16)up;
                float lo = up - (float)hi;
                astore(myb + 256 + 2 * w,     (u32)__builtin_bit_cast(u16, hi) | eph);
                astore(myb + 256 + 2 * w + 1, (u32)f2h_bits(lo) | eph);
                up_red = up;
            }
        }
        __syncthreads();                                   // B3 (zbuf/state WAR fence)
        if (pub && lane == 0 && tid < 192) upw_s[tid >> 6] = up_red;
    }
}

extern "C" void kernel_launch(void* const* d_in, const int* in_sizes, int n_in,
                              void* d_out, int out_size, void* d_ws, size_t ws_size,
                              hipStream_t stream) {
    const float* x  = (const float*)d_in[0];
    const float* ie = (const float*)d_in[1];
    const float* he = (const float*)d_in[2];
    const float* me = (const float*)d_in[3];
    const float* ik = (const float*)d_in[4];
    const float* hk = (const float*)d_in[5];
    const float* mk = (const float*)d_in[6];
    const float* at = (const float*)d_in[7];
    const float* bt = (const float*)d_in[8];

    u32*   hk2  = (u32*)d_ws;                   // 131072 u32 = 512 KB
    u32*   amk2 = hk2 + 256 * 512;              //  65536 u32 = 256 KB
    float* bmk  = (float*)(amk2 + 128 * 512);   //    512 f32 =   2 KB
    u32*   pkt  = (u32*)(bmk + 512);            // 2*64*4*288 u32 = 576 KB

    prep_hk<<<512, 256, 0, stream>>>(hk, hk2);
    prep_amk<<<129, 512, 0, stream>>>(mk, at, bt, amk2, bmk);
    lmu_main<<<N_B * KWG, 512, 0, stream>>>(x, ie, he, me, ik, bt, at,
                                            hk2, amk2, bmk, pkt, (float*)d_out);
}